// Round 4
// baseline (205.988 us; speedup 1.0000x reference)
//
#include <hip/hip_runtime.h>

// YOLO-v1-style loss, exact port of the JAX reference.
// S=7, B=2, C=20, channels per cell = 30 (120 B):
//   ch 0..19  : class scores
//   ch 20..24 : box0 x,y,w,h,conf
//   ch 25..29 : box1 x,y,w,h,conf
// Loss only touches channels 10..29 (cls uses [5*B:]=10.. — reference quirk).
//
// R4: request-rate fix. R3's per-cell float2 loads were 64-line-per-inst
// uncoalesced (TA/TCP request-bound at ~2.75 cyc/line-request). Now each
// wave loads its 64 cells' live 80 B regions coalesced (lane-consecutive
// float2s, ~13 lines/inst instead of 64), scatters through a wave-private
// LDS tile (cell stride 22 dwords, b64-aligned), reads back per-cell.

#define CH       30
#define EPSL     1e-6f
#define TPB      256
#define WAVES    (TPB / 64)
#define CSTRIDE  22                      // dwords per cell in LDS (20 live + 2 pad)
#define WTILE    (64 * CSTRIDE)          // dwords per wave tile (1408)

__device__ __forceinline__ float sgnf(float x) {
    return (x > 0.0f) ? 1.0f : ((x < 0.0f) ? -1.0f : 0.0f);
}

__global__ __launch_bounds__(TPB, 6) void yolo_loss_kernel(const float* __restrict__ p,
                                                           const float* __restrict__ a,
                                                           float* __restrict__ out,
                                                           long long n_cells) {
    __shared__ __align__(16) float sbuf[WAVES * WTILE];   // 22528 B
    __shared__ float wsum[WAVES];

    const int tid  = threadIdx.x;
    const int wave = tid >> 6;
    const int lane = tid & 63;

    const long long wave_cell0 = (long long)blockIdx.x * TPB + wave * 64;
    // cells this wave actually owns (64 except possibly the tail wave)
    int nc_wave = (int)min((long long)64, n_cells - wave_cell0);
    if (nc_wave < 0) nc_wave = 0;

    const char* pb = (const char*)p + wave_cell0 * 120LL;
    const char* ab = (const char*)a + wave_cell0 * 120LL;
    float* wbuf = &sbuf[wave * WTILE];

    // ---- coalesced loads of the live 80 B of each cell (both tensors up front) ----
    // float2 index i = lane + 64k  ->  cell c = i/10, slot s = i%10,
    // global byte offset = c*120 + 40 + 8s  (channels 10+2s, 11+2s)
    float2 rp[10], ra[10];
    int cc[10], ss[10];
#pragma unroll
    for (int k = 0; k < 10; ++k) {
        const int i = lane + 64 * k;
        const int c = i / 10;
        const int s = i - 10 * c;
        cc[k] = c; ss[k] = s;
        const int off = c * 120 + 40 + 8 * s;
        if (c < nc_wave) rp[k] = *(const float2*)(pb + off);
    }
#pragma unroll
    for (int k = 0; k < 10; ++k) {
        const int off = cc[k] * 120 + 40 + 8 * ss[k];
        if (cc[k] < nc_wave) ra[k] = *(const float2*)(ab + off);
    }

    // ---- phase 1: p through LDS (wave-private region; barriers for safety) ----
#pragma unroll
    for (int k = 0; k < 10; ++k)
        if (cc[k] < nc_wave)
            *(float2*)&wbuf[cc[k] * CSTRIDE + 2 * ss[k]] = rp[k];
    __syncthreads();

    float pd[20];
#pragma unroll
    for (int s = 0; s < 10; ++s) {
        const float2 v = *(const float2*)&wbuf[lane * CSTRIDE + 2 * s];
        pd[2 * s] = v.x; pd[2 * s + 1] = v.y;
    }
    __syncthreads();

    // ---- phase 2: a through the same LDS region ----
#pragma unroll
    for (int k = 0; k < 10; ++k)
        if (cc[k] < nc_wave)
            *(float2*)&wbuf[cc[k] * CSTRIDE + 2 * ss[k]] = ra[k];
    __syncthreads();

    float ad[20];
#pragma unroll
    for (int s = 0; s < 10; ++s) {
        const float2 v = *(const float2*)&wbuf[lane * CSTRIDE + 2 * s];
        ad[2 * s] = v.x; ad[2 * s + 1] = v.y;
    }

    // ---- per-cell loss (pd[j]/ad[j] = channel 10+j), exact as R3 ----
    float lsum = 0.0f;
    if (lane < nc_wave) {
        float pxv[2], pyv[2], pwv[2], phv[2], pcv[2];
        float axv[2], ayv[2], awv[2], ahv[2];
#pragma unroll
        for (int b = 0; b < 2; ++b) {
            pxv[b] = pd[10 + 5 * b]; pyv[b] = pd[11 + 5 * b];
            pwv[b] = pd[12 + 5 * b]; phv[b] = pd[13 + 5 * b];
            pcv[b] = pd[14 + 5 * b];
            axv[b] = ad[10 + 5 * b]; ayv[b] = ad[11 + 5 * b];
            awv[b] = ad[12 + 5 * b]; ahv[b] = ad[13 + 5 * b];
        }
        const bool obj = ad[14] > 0.0f;   // a's box-0 conf (channel 24)

        // pairwise IoU, max over target boxes
        float miou[2];
#pragma unroll
        for (int pb2 = 0; pb2 < 2; ++pb2) {
            const float p_tlx = pxv[pb2] - 0.5f * pwv[pb2];
            const float p_tly = pyv[pb2] - 0.5f * phv[pb2];
            const float p_brx = pxv[pb2] + 0.5f * pwv[pb2];
            const float p_bry = pyv[pb2] + 0.5f * phv[pb2];
            const float p_area = pwv[pb2] * phv[pb2];
            float best = -3.4e38f;
#pragma unroll
            for (int ab2 = 0; ab2 < 2; ++ab2) {
                const float a_tlx = axv[ab2] - 0.5f * awv[ab2];
                const float a_tly = ayv[ab2] - 0.5f * ahv[ab2];
                const float a_brx = axv[ab2] + 0.5f * awv[ab2];
                const float a_bry = ayv[ab2] + 0.5f * ahv[ab2];
                float sx = fminf(p_brx, a_brx) - fmaxf(p_tlx, a_tlx);
                float sy = fminf(p_bry, a_bry) - fmaxf(p_tly, a_tly);
                sx = fmaxf(sx, 0.0f);
                sy = fmaxf(sy, 0.0f);
                const float inter = sx * sy;
                const float uni = p_area + awv[ab2] * ahv[ab2] - inter;
                const float iou = (uni == 0.0f) ? 0.0f : (inter / uni);  // where(zero,0)/where(zero,eps)
                best = fmaxf(best, iou);
            }
            miou[pb2] = best;
        }
        const int resp = (miou[1] > miou[0]) ? 1 : 0;   // jnp.argmax first-max tie-break

        // coordinate / confidence losses
#pragma unroll
        for (int b = 0; b < 2; ++b) {
            const bool oij = obj && (b == resp);
            if (oij) {
                const float dx = axv[b] - pxv[b];
                const float dy = ayv[b] - pyv[b];
                const float dw = sgnf(awv[b]) * sqrtf(awv[b] + EPSL) - sgnf(pwv[b]) * sqrtf(pwv[b] + EPSL);
                const float dh = sgnf(ahv[b]) * sqrtf(ahv[b] + EPSL) - sgnf(phv[b]) * sqrtf(phv[b] + EPSL);
                const float dc = 1.0f - pcv[b];
                lsum += 5.0f * (dx * dx + dy * dy + dw * dw + dh * dh) + dc * dc;
            } else {
                lsum += 0.5f * pcv[b] * pcv[b];   // noobj: pc^2
            }
        }

        // "class" loss over channels 10..29 (indices 0..19), gated by obj_i
        if (obj) {
#pragma unroll
            for (int k = 0; k < 20; ++k) {
                const float d = pd[k] - ad[k];
                lsum += d * d;
            }
        }
    }

    // ---- reduction: wave shfl -> LDS -> one atomic per block ----
    float v = lsum;
#pragma unroll
    for (int off = 32; off > 0; off >>= 1)
        v += __shfl_down(v, off, 64);
    if (lane == 0) wsum[wave] = v;
    __syncthreads();
    if (tid == 0) {
        float t = 0.0f;
#pragma unroll
        for (int w = 0; w < WAVES; ++w) t += wsum[w];
        atomicAdd(out, t);
    }
}

extern "C" void kernel_launch(void* const* d_in, const int* in_sizes, int n_in,
                              void* d_out, int out_size, void* d_ws, size_t ws_size,
                              hipStream_t stream) {
    const float* p = (const float*)d_in[0];
    const float* a = (const float*)d_in[1];
    float* out = (float*)d_out;

    const long long n_cells = (long long)in_sizes[0] / CH;   // 16384*7*7 = 802816
    const int grid = (int)((n_cells + TPB - 1) / TPB);       // 3136, exact

    // d_out is re-poisoned (0xAA) before every timed replay -> must zero it here.
    hipMemsetAsync(d_out, 0, sizeof(float), stream);
    yolo_loss_kernel<<<grid, TPB, 0, stream>>>(p, a, out, n_cells);
}